// Round 1
// baseline (6783.276 us; speedup 1.0000x reference)
//
#include <hip/hip_runtime.h>
#include <math.h>

#define B_  512
#define T_  256
#define I_  64
#define H_  512
#define G4  2048
#define K_  576   // 512 (h) + 64 (x)
#define HN  30
#define EPSf 1e-5f

typedef __attribute__((ext_vector_type(8))) short short8;
typedef __attribute__((ext_vector_type(4))) float f32x4;

static __device__ __forceinline__ unsigned short f2bf(float f) {
    unsigned int u = __float_as_uint(f);
    u += 0x7fffu + ((u >> 16) & 1u);   // round-to-nearest-even
    return (unsigned short)(u >> 16);
}
static __device__ __forceinline__ float sigf(float x) {
    return __builtin_amdgcn_rcpf(1.0f + __expf(-x));
}
static __device__ __forceinline__ float tanh_f(float x) {
    float e = __expf(-2.0f * fabsf(x));
    float r = (1.0f - e) * __builtin_amdgcn_rcpf(1.0f + e);
    return copysignf(r, x);
}

// ---------------------------------------------------------------- pack / init
__global__ void pack_kernel(const float* __restrict__ x, const float* __restrict__ Wih,
                            const float* __restrict__ Whh, const float* __restrict__ bih,
                            const float* __restrict__ bhh,
                            unsigned short* __restrict__ Wp, unsigned short* __restrict__ xb,
                            float* __restrict__ bias, float* __restrict__ c,
                            unsigned short* __restrict__ hb0, float* __restrict__ a1p) {
    const int stride = gridDim.x * blockDim.x;
    const int g0 = blockIdx.x * blockDim.x + threadIdx.x;
    // W packed: Wp[n][k], k<512 from W_hh, k>=512 from W_ih  (k-contiguous rows)
    for (int idx = g0; idx < G4 * K_; idx += stride) {
        int n = idx / K_, k = idx - n * K_;
        float v = (k < H_) ? Whh[n * H_ + k] : Wih[n * I_ + (k - H_)];
        Wp[idx] = f2bf(v);
    }
    // x transposed+bf16: xb[t][b][i]
    for (int idx = g0; idx < T_ * B_ * I_; idx += stride) {
        int t = idx / (B_ * I_);
        int r = idx - t * (B_ * I_);
        int b = r / I_, i = r - b * I_;
        xb[idx] = f2bf(x[((size_t)b * T_ + t) * I_ + i]);
    }
    for (int idx = g0; idx < G4; idx += stride) bias[idx] = bih[idx] + bhh[idx];
    for (int idx = g0; idx < B_ * H_; idx += stride) { c[idx] = 0.0f; hb0[idx] = 0; }
    for (int idx = g0; idx < T_ * B_ * HN; idx += stride) a1p[idx] = 0.0f;
}

// ---------------------------------------------------------------- LSTM step
// grid: (16 j-blocks, 16 m-blocks), 256 threads (4 waves).
// Block computes gates tile [32 rows x (4 gates x 32 cols)], K=576, then the
// cell update (lane-local: all 4 gates for an (m,j) live in one lane), then
// the l1 partial contribution from its fp32 h tile (atomicAdd into a1p).
__global__ __launch_bounds__(256) void step_kernel(
        const unsigned short* __restrict__ Wp, const unsigned short* __restrict__ xbt,
        const float* __restrict__ bias, const unsigned short* __restrict__ hin,
        unsigned short* __restrict__ hout, float* __restrict__ c,
        float* __restrict__ a1pt, const float* __restrict__ l1w) {
    __shared__ unsigned short As[32][72];    // 144 B pitch: 16B-aligned, 2-way banks
    __shared__ unsigned short Bs[128][72];
    __shared__ float hs[32][33];

    const int tid = threadIdx.x;
    const int m0 = blockIdx.y * 32;
    const int j0 = blockIdx.x * 32;
    const int lane = tid & 63;
    const int wave = tid >> 6;
    const int wr = wave >> 1, wc = wave & 1;

    f32x4 acc[4];
#pragma unroll
    for (int g = 0; g < 4; ++g) acc[g] = (f32x4){0.f, 0.f, 0.f, 0.f};

    // staging decomposition
    const int arow = tid >> 3, aq = tid & 7;     // A: 32 rows x 8x(8 bf16)
    const int brow = tid >> 1, bhalf = tid & 1;  // B: 128 rows x 2x(32 bf16)
    const int bg = brow >> 5, bjj = brow & 31;
    const size_t bsrcrow = (size_t)(bg * H_ + j0 + bjj) * K_;

    for (int kc = 0; kc < 9; ++kc) {
        const int k0 = kc * 64;
        const unsigned short* asrc = (kc < 8)
            ? (hin + (size_t)(m0 + arow) * H_ + k0 + aq * 8)
            : (xbt + (size_t)(m0 + arow) * I_ + aq * 8);
        *reinterpret_cast<short8*>(&As[arow][aq * 8]) =
            *reinterpret_cast<const short8*>(asrc);
        const unsigned short* bsrc = Wp + bsrcrow + k0 + bhalf * 32;
#pragma unroll
        for (int w8 = 0; w8 < 4; ++w8)
            *reinterpret_cast<short8*>(&Bs[brow][bhalf * 32 + w8 * 8]) =
                *reinterpret_cast<const short8*>(bsrc + w8 * 8);
        __syncthreads();
#pragma unroll
        for (int ks = 0; ks < 2; ++ks) {
            const int kk = ks * 32 + (lane >> 4) * 8;
            short8 af = *reinterpret_cast<const short8*>(&As[wr * 16 + (lane & 15)][kk]);
#pragma unroll
            for (int g = 0; g < 4; ++g) {
                short8 bfr = *reinterpret_cast<const short8*>(
                    &Bs[g * 32 + wc * 16 + (lane & 15)][kk]);
                acc[g] = __builtin_amdgcn_mfma_f32_16x16x32_bf16(af, bfr, acc[g], 0, 0, 0);
            }
        }
        __syncthreads();
    }

    // cell update; D-frag mapping: col = lane&15, row = (lane>>4)*4 + reg
    const int jl = lane & 15;
    const int j = j0 + wc * 16 + jl;
    const float bi = bias[j];
    const float bf_ = bias[H_ + j];
    const float bg_ = bias[2 * H_ + j];
    const float bo_ = bias[3 * H_ + j];
    const int rbase = wr * 16 + (lane >> 4) * 4;
#pragma unroll
    for (int rr = 0; rr < 4; ++rr) {
        const int m = m0 + rbase + rr;
        float ig = acc[0][rr] + bi;
        float fg = acc[1][rr] + bf_;
        float gg = acc[2][rr] + bg_;
        float og = acc[3][rr] + bo_;
        size_t ci = (size_t)m * H_ + j;
        float cn = sigf(fg) * c[ci] + sigf(ig) * tanh_f(gg);
        c[ci] = cn;
        float hn = sigf(og) * tanh_f(cn);
        hout[ci] = f2bf(hn);
        hs[rbase + rr][wc * 16 + jl] = hn;     // fp32 h for the l1 partial
    }
    __syncthreads();

    // l1 partial: a1p[m][f] += sum_j hs[m][j] * l1_w[f][j0+j]
    const int mloc = tid & 31, f4 = tid >> 5;   // 8 groups x 4 features
    float pacc[4] = {0.f, 0.f, 0.f, 0.f};
    for (int jj = 0; jj < 32; ++jj) {
        float hv = hs[mloc][jj];
#pragma unroll
        for (int q = 0; q < 4; ++q) {
            int f = f4 * 4 + q;
            if (f < HN) pacc[q] = fmaf(hv, l1w[f * H_ + j0 + jj], pacc[q]);
        }
    }
#pragma unroll
    for (int q = 0; q < 4; ++q) {
        int f = f4 * 4 + q;
        if (f < HN) atomicAdd(&a1pt[(size_t)(m0 + mloc) * HN + f], pacc[q]);
    }
}

// ---------------------------------------------------------------- MLP head
static __device__ __forceinline__ void bn_relu30(float v[HN], const float* __restrict__ gamma,
                                                 const float* __restrict__ beta,
                                                 float (*pS)[HN], float (*pQ)[HN]) {
    float s0[HN], s1[HN];
#pragma unroll
    for (int f = 0; f < HN; ++f) { s0[f] = v[f]; s1[f] = v[f] * v[f]; }
#pragma unroll
    for (int off = 32; off >= 1; off >>= 1) {
#pragma unroll
        for (int f = 0; f < HN; ++f) {
            s0[f] += __shfl_xor(s0[f], off);
            s1[f] += __shfl_xor(s1[f], off);
        }
    }
    const int lane = threadIdx.x & 63, w = threadIdx.x >> 6;
    if (lane == 0) {
#pragma unroll
        for (int f = 0; f < HN; ++f) { pS[w][f] = s0[f]; pQ[w][f] = s1[f]; }
    }
    __syncthreads();
#pragma unroll
    for (int f = 0; f < HN; ++f) {
        float S = 0.f, Q = 0.f;
#pragma unroll
        for (int u = 0; u < 8; ++u) { S += pS[u][f]; Q += pQ[u][f]; }
        float m = S * (1.0f / 512.0f);
        float var = Q * (1.0f / 512.0f) - m * m;     // biased, matches jnp.mean
        float inv = 1.0f / sqrtf(var + EPSf);
        float tv = gamma[f] * (v[f] - m) * inv + beta[f];
        v[f] = fmaxf(tv, 0.f);
    }
    __syncthreads();
}

static __device__ __forceinline__ void layer30(float v[HN], const float* __restrict__ w) {
    float u[HN];
#pragma unroll
    for (int f = 0; f < HN; ++f) {
        float a = 0.f;
#pragma unroll
        for (int k = 0; k < HN; ++k) a = fmaf(v[k], w[f * HN + k], a);
        u[f] = a;
    }
#pragma unroll
    for (int f = 0; f < HN; ++f) v[f] = u[f];
}

__global__ __launch_bounds__(512) void mlp_kernel(
        const float* __restrict__ a1p, const float* __restrict__ l1b,
        const float* __restrict__ l2w, const float* __restrict__ l3w,
        const float* __restrict__ l4w, const float* __restrict__ l5w,
        const float* __restrict__ gamma, const float* __restrict__ beta,
        float* __restrict__ out) {
    const int t = blockIdx.x;
    const int b = threadIdx.x;
    __shared__ float pS[8][HN], pQ[8][HN];
    float v[HN];
    const float* src = a1p + ((size_t)t * B_ + b) * HN;
#pragma unroll
    for (int f = 0; f < HN; ++f) v[f] = src[f] + l1b[f];
    bn_relu30(v, gamma, beta, pS, pQ);
    layer30(v, l2w); bn_relu30(v, gamma, beta, pS, pQ);
    layer30(v, l3w); bn_relu30(v, gamma, beta, pS, pQ);
    layer30(v, l4w); bn_relu30(v, gamma, beta, pS, pQ);
    float o0 = 0.f, o1 = 0.f;
#pragma unroll
    for (int k = 0; k < HN; ++k) {
        o0 = fmaf(v[k], l5w[k], o0);
        o1 = fmaf(v[k], l5w[HN + k], o1);
    }
    out[(size_t)b * (2 * T_) + t]      = o0;   // out[b][0][t]
    out[(size_t)b * (2 * T_) + T_ + t] = o1;   // out[b][1][t]
}

// ---------------------------------------------------------------- launch
extern "C" void kernel_launch(void* const* d_in, const int* in_sizes, int n_in,
                              void* d_out, int out_size, void* d_ws, size_t ws_size,
                              hipStream_t stream) {
    const float* x    = (const float*)d_in[0];
    const float* Wih  = (const float*)d_in[1];
    const float* Whh  = (const float*)d_in[2];
    const float* bih  = (const float*)d_in[3];
    const float* bhh  = (const float*)d_in[4];
    const float* l1w  = (const float*)d_in[5];
    const float* l1b  = (const float*)d_in[6];
    const float* l2w  = (const float*)d_in[7];
    const float* l3w  = (const float*)d_in[8];
    const float* l4w  = (const float*)d_in[9];
    const float* l5w  = (const float*)d_in[10];
    const float* gam  = (const float*)d_in[11];
    const float* bet  = (const float*)d_in[12];
    float* out = (float*)d_out;

    char* ws = (char*)d_ws;
    unsigned short* Wp  = (unsigned short*)ws;  ws += (size_t)G4 * K_ * 2;        // 2.36 MB
    unsigned short* xb  = (unsigned short*)ws;  ws += (size_t)T_ * B_ * I_ * 2;   // 16.8 MB
    float*          bia = (float*)ws;           ws += (size_t)G4 * 4;             // 8 KB
    float*          c   = (float*)ws;           ws += (size_t)B_ * H_ * 4;        // 1 MB
    unsigned short* hb  = (unsigned short*)ws;  ws += (size_t)2 * B_ * H_ * 2;    // 1 MB
    float*          a1p = (float*)ws;           ws += (size_t)T_ * B_ * HN * 4;   // 15.7 MB

    pack_kernel<<<1024, 256, 0, stream>>>(x, Wih, Whh, bih, bhh, Wp, xb, bia, c, hb, a1p);

    for (int t = 0; t < T_; ++t) {
        const unsigned short* hin = hb + (size_t)(t & 1) * B_ * H_;
        unsigned short* hout      = hb + (size_t)((t + 1) & 1) * B_ * H_;
        step_kernel<<<dim3(16, 16), 256, 0, stream>>>(
            Wp, xb + (size_t)t * B_ * I_, bia, hin, hout, c,
            a1p + (size_t)t * B_ * HN, l1w);
    }

    mlp_kernel<<<T_, 512, 0, stream>>>(a1p, l1b, l2w, l3w, l4w, l5w, gam, bet, out);
}